// Round 1
// baseline (280.534 us; speedup 1.0000x reference)
//
#include <hip/hip_runtime.h>
#include <math.h>

#define DKD 256
#define DVD 256

constexpr int TPB = 256;
constexpr int NB  = 1024;   // M / RPB blocks; exactly 4 blocks/CU co-resident
constexpr int RPB = 128;    // rows per block (M = 131072)

// ---- Kernel F: fused flash-style single pass over K and V ----
// Per block b (128 rows):
//   phase 1: logits for the block's rows (wave-parallel dot + shuffle reduce),
//            block max m_b, e[r] = exp(l_r - m_b) in LDS, S_b = sum e
//   phase 2: acc[j] += e[r] * V[r,j]  (pure V stream, weights from LDS)
//   phase 3: cross-wave reduce, write partT[j][b] (transposed for combine), m_b, S_b
__global__ __launch_bounds__(TPB, 4) void k_fused(
    const float* __restrict__ q,
    const float* __restrict__ K,
    const float* __restrict__ V,
    float* __restrict__ partT,   // [DVD][NB]
    float* __restrict__ pmax,    // [NB]
    float* __restrict__ psum)    // [NB]
{
    __shared__ __align__(16) float s_l[RPB];   // logits, then exp(l - m_b)
    __shared__ float  s_wred[4];
    __shared__ float4 s_acc[4][64];

    const int t    = threadIdx.x;
    const int lane = t & 63;
    const int wave = t >> 6;
    const int b    = blockIdx.x;

    const float4* __restrict__ K4 = (const float4*)K;
    const float4* __restrict__ V4 = (const float4*)V;
    const float4 q4 = ((const float4*)q)[lane];

    const int wbeg = b * RPB + wave * (RPB / 4);   // 32 rows per wave

    // ---- Phase 1: logits ----
    float wmax = -INFINITY;
    #pragma unroll 2
    for (int it = 0; it < 8; ++it) {               // 8 iters x 4 rows
        const int r = wbeg + it * 4;
        const size_t base = (size_t)r * 64 + lane;
        float4 k0 = K4[base];
        float4 k1 = K4[base + 64];
        float4 k2 = K4[base + 128];
        float4 k3 = K4[base + 192];

        float s0 = k0.x*q4.x + k0.y*q4.y + k0.z*q4.z + k0.w*q4.w;
        float s1 = k1.x*q4.x + k1.y*q4.y + k1.z*q4.z + k1.w*q4.w;
        float s2 = k2.x*q4.x + k2.y*q4.y + k2.z*q4.z + k2.w*q4.w;
        float s3 = k3.x*q4.x + k3.y*q4.y + k3.z*q4.z + k3.w*q4.w;

        #pragma unroll
        for (int off = 32; off > 0; off >>= 1) {
            s0 += __shfl_xor(s0, off);
            s1 += __shfl_xor(s1, off);
            s2 += __shfl_xor(s2, off);
            s3 += __shfl_xor(s3, off);
        }
        wmax = fmaxf(wmax, fmaxf(fmaxf(s0, s1), fmaxf(s2, s3)));
        if (lane < 4) {
            const float sv = lane == 0 ? s0 : lane == 1 ? s1 : lane == 2 ? s2 : s3;
            s_l[wave * 32 + it * 4 + lane] = sv;
        }
    }
    if (lane == 0) s_wred[wave] = wmax;
    __syncthreads();

    const float mb = fmaxf(fmaxf(s_wred[0], s_wred[1]), fmaxf(s_wred[2], s_wred[3]));

    // exp in place; wave 0 produces the block partial sum
    if (t < RPB) s_l[t] = __expf(s_l[t] - mb);
    __syncthreads();
    if (wave == 0) {
        float es = s_l[lane] + s_l[lane + 64];
        #pragma unroll
        for (int off = 32; off > 0; off >>= 1) es += __shfl_xor(es, off);
        if (lane == 0) { pmax[b] = mb; psum[b] = es; }
    }

    // ---- Phase 2: weighted V accumulation ----
    float4 acc = make_float4(0.f, 0.f, 0.f, 0.f);
    const int ebase = wave * 32;
    #pragma unroll 2
    for (int it = 0; it < 8; ++it) {
        const int r = wbeg + it * 4;
        const size_t base = (size_t)r * 64 + lane;
        const float4 w4 = *(const float4*)&s_l[ebase + it * 4];   // LDS broadcast
        float4 v0 = V4[base];
        float4 v1 = V4[base + 64];
        float4 v2 = V4[base + 128];
        float4 v3 = V4[base + 192];

        acc.x += w4.x*v0.x + w4.y*v1.x + w4.z*v2.x + w4.w*v3.x;
        acc.y += w4.x*v0.y + w4.y*v1.y + w4.z*v2.y + w4.w*v3.y;
        acc.z += w4.x*v0.z + w4.y*v1.z + w4.z*v2.z + w4.w*v3.z;
        acc.w += w4.x*v0.w + w4.y*v1.w + w4.z*v2.w + w4.w*v3.w;
    }

    // ---- Phase 3: cross-wave reduce, transposed store ----
    s_acc[wave][lane] = acc;
    __syncthreads();
    float yv = 0.f;
    const float* saf = (const float*)&s_acc[0][0];
    #pragma unroll
    for (int ww = 0; ww < 4; ++ww) yv += saf[ww * DVD + t];
    partT[(size_t)t * NB + b] = yv;
}

// ---- Kernel C: out[j] = (sum_b exp(m_b - M) * partT[j][b]) / (sum_b exp(m_b - M) * S_b) ----
__global__ __launch_bounds__(TPB) void k_combine(
    const float* __restrict__ partT,
    const float* __restrict__ pmax,
    const float* __restrict__ psum,
    float* __restrict__ out)
{
    __shared__ float red[TPB];
    __shared__ __align__(16) float s_a[NB];   // alpha_b = exp(m_b - M)
    const int t = threadIdx.x;

    // global max over 1024 block maxima (4 per thread)
    const float4 pm = ((const float4*)pmax)[t];
    float lm = fmaxf(fmaxf(pm.x, pm.y), fmaxf(pm.z, pm.w));
    red[t] = lm; __syncthreads();
    for (int s = TPB / 2; s > 0; s >>= 1) {
        if (t < s) red[t] = fmaxf(red[t], red[t + s]);
        __syncthreads();
    }
    const float Mg = red[0];
    __syncthreads();

    // alpha into LDS; L = sum alpha_b * S_b
    const float4 ps = ((const float4*)psum)[t];
    float4 a;
    a.x = __expf(pm.x - Mg); a.y = __expf(pm.y - Mg);
    a.z = __expf(pm.z - Mg); a.w = __expf(pm.w - Mg);
    ((float4*)s_a)[t] = a;
    red[t] = a.x*ps.x + a.y*ps.y + a.z*ps.z + a.w*ps.w;
    __syncthreads();
    for (int s = TPB / 2; s > 0; s >>= 1) {
        if (t < s) red[t] += red[t + s];
        __syncthreads();
    }
    const float invL = 1.0f / red[0];
    __syncthreads();

    // y_j = sum_b alpha_b * partT[j][b]
    const int j = blockIdx.x;
    const float4 v  = ((const float4*)(partT + (size_t)j * NB))[t];
    const float4 av = ((const float4*)s_a)[t];
    red[t] = v.x*av.x + v.y*av.y + v.z*av.z + v.w*av.w;
    __syncthreads();
    for (int s = TPB / 2; s > 0; s >>= 1) {
        if (t < s) red[t] += red[t + s];
        __syncthreads();
    }
    if (t == 0) out[j] = red[0] * invL;
}

extern "C" void kernel_launch(void* const* d_in, const int* in_sizes, int n_in,
                              void* d_out, int out_size, void* d_ws, size_t ws_size,
                              hipStream_t stream) {
    const float* q = (const float*)d_in[0];
    const float* K = (const float*)d_in[1];
    const float* V = (const float*)d_in[2];
    float* out = (float*)d_out;

    // ws: partT[DVD*NB] | pmax[NB] | psum[NB]
    float* ws    = (float*)d_ws;
    float* partT = ws;
    float* pmax  = partT + (size_t)DVD * NB;
    float* psum  = pmax + NB;

    k_fused  <<<NB,  TPB, 0, stream>>>(q, K, V, partT, pmax, psum);
    k_combine<<<DVD, TPB, 0, stream>>>(partT, pmax, psum, out);
}

// Round 2
// 279.712 us; speedup vs baseline: 1.0029x; 1.0029x over previous
//
#include <hip/hip_runtime.h>
#include <math.h>

#define DKD 256
#define DVD 256

constexpr int TPB  = 512;           // 8 waves/block
constexpr int NB   = 1024;          // 4 blocks/CU co-resident
constexpr int RPB  = 128;           // rows per block (M = 131072)
constexpr int WPB  = TPB / 64;      // 8 waves
constexpr int RPW  = RPB / WPB;     // 16 rows per wave
constexpr int TPBC = 256;           // combine kernel block size

// ---- Fused flash-style kernel ----
// Phase 1: pure K stream; per-lane 4-elem partial dots -> LDS (rotated cols, no shuffles in loop)
// Phase 1b: one LDS reduction pass (4 threads/row, 16 reads + 2 shuffle stages)
// Phase 2: pure V stream weighted by exp(l - m_b) from LDS
// Phase 3: cross-wave reduce, transposed store of partials
__global__ __launch_bounds__(TPB, 8) void k_fused(
    const float* __restrict__ q,
    const float* __restrict__ K,
    const float* __restrict__ V,
    float* __restrict__ partT,   // [DVD][NB]
    float* __restrict__ pmax,    // [NB]
    float* __restrict__ psum)    // [NB]
{
    __shared__ __align__(16) float s_buf[RPB * 64];  // 32 KB: partials, then reused as acc
    __shared__ __align__(16) float s_l[RPB];
    __shared__ float s_wred[WPB];

    const int t    = threadIdx.x;
    const int lane = t & 63;
    const int wave = t >> 6;
    const int b    = blockIdx.x;

    const float4* __restrict__ K4 = (const float4*)K;
    const float4* __restrict__ V4 = (const float4*)V;
    const float4 q4 = ((const float4*)q)[lane];

    const int lbeg = wave * RPW;          // local row base for this wave
    const int gbeg = b * RPB + lbeg;      // global row base

    // ---- Phase 1: K stream, partials to LDS (no cross-lane ops in loop) ----
    #pragma unroll 2
    for (int it = 0; it < RPW / 4; ++it) {           // 4 iters x 4 rows
        const int lr = lbeg + it * 4;
        const size_t base = (size_t)(gbeg + it * 4) * 64 + lane;
        float4 k0 = K4[base];
        float4 k1 = K4[base + 64];
        float4 k2 = K4[base + 128];
        float4 k3 = K4[base + 192];

        float s0 = k0.x*q4.x + k0.y*q4.y + k0.z*q4.z + k0.w*q4.w;
        float s1 = k1.x*q4.x + k1.y*q4.y + k1.z*q4.z + k1.w*q4.w;
        float s2 = k2.x*q4.x + k2.y*q4.y + k2.z*q4.z + k2.w*q4.w;
        float s3 = k3.x*q4.x + k3.y*q4.y + k3.z*q4.z + k3.w*q4.w;

        // rotate-by-row column: write bank = (lane+lr)%32 -> 2 lanes/bank (free)
        s_buf[(lr + 0) * 64 + ((lane + lr + 0) & 63)] = s0;
        s_buf[(lr + 1) * 64 + ((lane + lr + 1) & 63)] = s1;
        s_buf[(lr + 2) * 64 + ((lane + lr + 2) & 63)] = s2;
        s_buf[(lr + 3) * 64 + ((lane + lr + 3) & 63)] = s3;
    }
    __syncthreads();

    // ---- Phase 1b: reduce 64 partials per row; 4 threads per row ----
    const int row = t >> 2;               // 0..127 local row
    const int qtr = t & 3;
    float rs = 0.f;
    const int cbase = qtr * 16;
    #pragma unroll
    for (int i = 0; i < 16; ++i)
        rs += s_buf[row * 64 + ((cbase + i + row) & 63)];
    rs += __shfl_xor(rs, 1);
    rs += __shfl_xor(rs, 2);              // all 4 threads now hold the row logit

    // wave max over this wave's 16 rows (groups of 4 already equal)
    float wm = rs;
    #pragma unroll
    for (int off = 4; off < 64; off <<= 1) wm = fmaxf(wm, __shfl_xor(wm, off));
    if (lane == 0) s_wred[wave] = wm;
    if (qtr == 0) s_l[row] = rs;
    __syncthreads();

    float mb = s_wred[0];
    #pragma unroll
    for (int wv = 1; wv < WPB; ++wv) mb = fmaxf(mb, s_wred[wv]);

    if (t < RPB) s_l[t] = __expf(s_l[t] - mb);
    __syncthreads();

    if (wave == 0) {
        float es = s_l[lane] + s_l[lane + 64];
        #pragma unroll
        for (int off = 32; off > 0; off >>= 1) es += __shfl_xor(es, off);
        if (lane == 0) { pmax[b] = mb; psum[b] = es; }
    }

    // ---- Phase 2: V stream weighted by LDS broadcasts ----
    float4 acc = make_float4(0.f, 0.f, 0.f, 0.f);
    #pragma unroll 2
    for (int it = 0; it < RPW / 4; ++it) {
        const size_t base = (size_t)(gbeg + it * 4) * 64 + lane;
        const float4 w4 = *(const float4*)&s_l[lbeg + it * 4];   // wave-uniform broadcast
        float4 v0 = V4[base];
        float4 v1 = V4[base + 64];
        float4 v2 = V4[base + 128];
        float4 v3 = V4[base + 192];

        acc.x += w4.x*v0.x + w4.y*v1.x + w4.z*v2.x + w4.w*v3.x;
        acc.y += w4.x*v0.y + w4.y*v1.y + w4.z*v2.y + w4.w*v3.y;
        acc.z += w4.x*v0.z + w4.y*v1.z + w4.z*v2.z + w4.w*v3.z;
        acc.w += w4.x*v0.w + w4.y*v1.w + w4.z*v2.w + w4.w*v3.w;
    }

    // ---- Phase 3: cross-wave reduce (reuse s_buf), transposed store ----
    // safe: last s_buf reads happened before the exp __syncthreads
    float4* s_acc = (float4*)s_buf;
    s_acc[wave * 64 + lane] = acc;
    __syncthreads();
    if (t < DVD) {
        const float* saf = (const float*)s_acc;   // [WPB][256]
        float yv = 0.f;
        #pragma unroll
        for (int wv = 0; wv < WPB; ++wv) yv += saf[wv * DVD + t];
        partT[(size_t)t * NB + b] = yv;
    }
}

// ---- Combine: out[j] = (sum_b a_b * partT[j][b]) / (sum_b a_b * S_b), a_b = exp(m_b - M) ----
__global__ __launch_bounds__(TPBC) void k_combine(
    const float* __restrict__ partT,
    const float* __restrict__ pmax,
    const float* __restrict__ psum,
    float* __restrict__ out)
{
    __shared__ float red[TPBC];
    __shared__ __align__(16) float s_a[NB];
    const int t = threadIdx.x;

    const float4 pm = ((const float4*)pmax)[t];
    float lm = fmaxf(fmaxf(pm.x, pm.y), fmaxf(pm.z, pm.w));
    red[t] = lm; __syncthreads();
    for (int s = TPBC / 2; s > 0; s >>= 1) {
        if (t < s) red[t] = fmaxf(red[t], red[t + s]);
        __syncthreads();
    }
    const float Mg = red[0];
    __syncthreads();

    const float4 ps = ((const float4*)psum)[t];
    float4 a;
    a.x = __expf(pm.x - Mg); a.y = __expf(pm.y - Mg);
    a.z = __expf(pm.z - Mg); a.w = __expf(pm.w - Mg);
    ((float4*)s_a)[t] = a;
    red[t] = a.x*ps.x + a.y*ps.y + a.z*ps.z + a.w*ps.w;
    __syncthreads();
    for (int s = TPBC / 2; s > 0; s >>= 1) {
        if (t < s) red[t] += red[t + s];
        __syncthreads();
    }
    const float invL = 1.0f / red[0];
    __syncthreads();

    const int j = blockIdx.x;
    const float4 v  = ((const float4*)(partT + (size_t)j * NB))[t];
    const float4 av = ((const float4*)s_a)[t];
    red[t] = v.x*av.x + v.y*av.y + v.z*av.z + v.w*av.w;
    __syncthreads();
    for (int s = TPBC / 2; s > 0; s >>= 1) {
        if (t < s) red[t] += red[t + s];
        __syncthreads();
    }
    if (t == 0) out[j] = red[0] * invL;
}

extern "C" void kernel_launch(void* const* d_in, const int* in_sizes, int n_in,
                              void* d_out, int out_size, void* d_ws, size_t ws_size,
                              hipStream_t stream) {
    const float* q = (const float*)d_in[0];
    const float* K = (const float*)d_in[1];
    const float* V = (const float*)d_in[2];
    float* out = (float*)d_out;

    // ws: partT[DVD*NB] | pmax[NB] | psum[NB]
    float* ws    = (float*)d_ws;
    float* partT = ws;
    float* pmax  = partT + (size_t)DVD * NB;
    float* psum  = pmax + NB;

    k_fused  <<<NB,   TPB,  0, stream>>>(q, K, V, partT, pmax, psum);
    k_combine<<<DVD,  TPBC, 0, stream>>>(partT, pmax, psum, out);
}